// Round 1
// baseline (1333.919 us; speedup 1.0000x reference)
//
#include <hip/hip_runtime.h>
#include <cstddef>

#define S_LEN 2048
#define D_MODEL 512
#define NHEAD 8
#define DH 64
#define FF_DIM 2048
#define L_TAGS 32
#define START_TAG 30
#define STOP_TAG 31
#define NEGV (-10000.0f)

// ---------------- embedding gather ----------------
__global__ __launch_bounds__(128) void k_embed(const int* __restrict__ sent,
                                               const float* __restrict__ embed,
                                               float* __restrict__ x) {
  int s = blockIdx.x;
  int d = threadIdx.x * 4;
  size_t idx = (size_t)sent[s] * D_MODEL + d;
  *(float4*)(x + (size_t)s * D_MODEL + d) = *(const float4*)(embed + idx);
}

// ---------------- GEMM C[M][N] = A[M][K] * B[N][K]^T + bias, 128x128 tile ----------------
template <bool RELU>
__global__ __launch_bounds__(256) void k_gemm128(const float* __restrict__ A,
                                                 const float* __restrict__ B,
                                                 const float* __restrict__ bias,
                                                 float* __restrict__ C,
                                                 int M, int N, int K) {
  __shared__ float As[16][132];
  __shared__ float Bs[16][132];
  const int tid = threadIdx.x;
  const int bm = blockIdx.y * 128, bn = blockIdx.x * 128;
  const int lrow = tid >> 1;
  const int lks = (tid & 1) * 8;
  const int row0 = (tid >> 4) * 8;
  const int col0 = (tid & 15) * 8;
  float acc[8][8] = {};
  for (int k0 = 0; k0 < K; k0 += 16) {
    float4 a0 = *(const float4*)(A + (size_t)(bm + lrow) * K + k0 + lks);
    float4 a1 = *(const float4*)(A + (size_t)(bm + lrow) * K + k0 + lks + 4);
    float4 b0 = *(const float4*)(B + (size_t)(bn + lrow) * K + k0 + lks);
    float4 b1 = *(const float4*)(B + (size_t)(bn + lrow) * K + k0 + lks + 4);
    __syncthreads();
    As[lks + 0][lrow] = a0.x; As[lks + 1][lrow] = a0.y;
    As[lks + 2][lrow] = a0.z; As[lks + 3][lrow] = a0.w;
    As[lks + 4][lrow] = a1.x; As[lks + 5][lrow] = a1.y;
    As[lks + 6][lrow] = a1.z; As[lks + 7][lrow] = a1.w;
    Bs[lks + 0][lrow] = b0.x; Bs[lks + 1][lrow] = b0.y;
    Bs[lks + 2][lrow] = b0.z; Bs[lks + 3][lrow] = b0.w;
    Bs[lks + 4][lrow] = b1.x; Bs[lks + 5][lrow] = b1.y;
    Bs[lks + 6][lrow] = b1.z; Bs[lks + 7][lrow] = b1.w;
    __syncthreads();
#pragma unroll
    for (int kk = 0; kk < 16; ++kk) {
      float4 av0 = *(const float4*)&As[kk][row0];
      float4 av1 = *(const float4*)&As[kk][row0 + 4];
      float4 bv0 = *(const float4*)&Bs[kk][col0];
      float4 bv1 = *(const float4*)&Bs[kk][col0 + 4];
      float ar[8] = {av0.x, av0.y, av0.z, av0.w, av1.x, av1.y, av1.z, av1.w};
      float br[8] = {bv0.x, bv0.y, bv0.z, bv0.w, bv1.x, bv1.y, bv1.z, bv1.w};
#pragma unroll
      for (int i = 0; i < 8; ++i)
#pragma unroll
        for (int j = 0; j < 8; ++j) acc[i][j] += ar[i] * br[j];
    }
  }
#pragma unroll
  for (int i = 0; i < 8; ++i) {
    int r = bm + row0 + i;
    float4 o0, o1;
    o0.x = acc[i][0] + bias[bn + col0 + 0];
    o0.y = acc[i][1] + bias[bn + col0 + 1];
    o0.z = acc[i][2] + bias[bn + col0 + 2];
    o0.w = acc[i][3] + bias[bn + col0 + 3];
    o1.x = acc[i][4] + bias[bn + col0 + 4];
    o1.y = acc[i][5] + bias[bn + col0 + 5];
    o1.z = acc[i][6] + bias[bn + col0 + 6];
    o1.w = acc[i][7] + bias[bn + col0 + 7];
    if (RELU) {
      o0.x = fmaxf(o0.x, 0.f); o0.y = fmaxf(o0.y, 0.f);
      o0.z = fmaxf(o0.z, 0.f); o0.w = fmaxf(o0.w, 0.f);
      o1.x = fmaxf(o1.x, 0.f); o1.y = fmaxf(o1.y, 0.f);
      o1.z = fmaxf(o1.z, 0.f); o1.w = fmaxf(o1.w, 0.f);
    }
    *(float4*)(C + (size_t)r * N + bn + col0) = o0;
    *(float4*)(C + (size_t)r * N + bn + col0 + 4) = o1;
  }
}

// ---------------- GEMM 64x64 tile (for N=512 cases) ----------------
template <bool RELU>
__global__ __launch_bounds__(256) void k_gemm64(const float* __restrict__ A,
                                                const float* __restrict__ B,
                                                const float* __restrict__ bias,
                                                float* __restrict__ C,
                                                int M, int N, int K) {
  __shared__ float As[16][68];
  __shared__ float Bs[16][68];
  const int tid = threadIdx.x;
  const int bm = blockIdx.y * 64, bn = blockIdx.x * 64;
  const int tx = tid & 15, ty = tid >> 4;
  const int lr = tid >> 2, lk = (tid & 3) * 4;
  float acc[4][4] = {};
  for (int k0 = 0; k0 < K; k0 += 16) {
    float4 a4 = *(const float4*)(A + (size_t)(bm + lr) * K + k0 + lk);
    float4 b4 = *(const float4*)(B + (size_t)(bn + lr) * K + k0 + lk);
    __syncthreads();
    As[lk + 0][lr] = a4.x; As[lk + 1][lr] = a4.y;
    As[lk + 2][lr] = a4.z; As[lk + 3][lr] = a4.w;
    Bs[lk + 0][lr] = b4.x; Bs[lk + 1][lr] = b4.y;
    Bs[lk + 2][lr] = b4.z; Bs[lk + 3][lr] = b4.w;
    __syncthreads();
#pragma unroll
    for (int kk = 0; kk < 16; ++kk) {
      float4 av = *(const float4*)&As[kk][ty * 4];
      float4 bv = *(const float4*)&Bs[kk][tx * 4];
      float ar[4] = {av.x, av.y, av.z, av.w};
      float br[4] = {bv.x, bv.y, bv.z, bv.w};
#pragma unroll
      for (int i = 0; i < 4; ++i)
#pragma unroll
        for (int j = 0; j < 4; ++j) acc[i][j] += ar[i] * br[j];
    }
  }
#pragma unroll
  for (int i = 0; i < 4; ++i) {
    float4 o;
    o.x = acc[i][0] + bias[bn + tx * 4 + 0];
    o.y = acc[i][1] + bias[bn + tx * 4 + 1];
    o.z = acc[i][2] + bias[bn + tx * 4 + 2];
    o.w = acc[i][3] + bias[bn + tx * 4 + 3];
    if (RELU) {
      o.x = fmaxf(o.x, 0.f); o.y = fmaxf(o.y, 0.f);
      o.z = fmaxf(o.z, 0.f); o.w = fmaxf(o.w, 0.f);
    }
    *(float4*)(C + (size_t)(bm + ty * 4 + i) * N + bn + tx * 4) = o;
  }
}

// ---------------- fused attention (per head, 64-query tiles, online softmax) ----------------
__global__ __launch_bounds__(256) void k_attn(const float* __restrict__ qkv,
                                              float* __restrict__ ob) {
  __shared__ float Qs[64][68];
  __shared__ float KVs[64][68];
  __shared__ float Ss[64][68];
  __shared__ float PM[64][8];
  __shared__ float PS[64][8];
  const int tid = threadIdx.x;
  const int bq = blockIdx.x * 64;
  const int h = blockIdx.y;
  const int lrow = tid >> 2, lseg = (tid & 3) * 16;
  {
    const float* src = qkv + (size_t)(bq + lrow) * 1536 + h * DH + lseg;
#pragma unroll
    for (int i = 0; i < 4; ++i) {
      float4 v = *(const float4*)(src + i * 4);
      v.x *= 0.125f; v.y *= 0.125f; v.z *= 0.125f; v.w *= 0.125f;
      *(float4*)&Qs[lrow][lseg + i * 4] = v;
    }
  }
  const int u = tid & 7, rp = tid >> 3;
  const int r0 = rp * 2, r1 = r0 + 1, db = u * 8;
  float m0 = -1e30f, m1 = -1e30f, l0 = 0.f, l1 = 0.f;
  float acc0[8] = {}, acc1[8] = {};
  for (int kt = 0; kt < 32; ++kt) {
    __syncthreads();
    float4 vr[4];
    {
      const float* ksrc = qkv + (size_t)(kt * 64 + lrow) * 1536 + 512 + h * DH + lseg;
#pragma unroll
      for (int i = 0; i < 4; ++i)
        *(float4*)&KVs[lrow][lseg + i * 4] = *(const float4*)(ksrc + i * 4);
      const float* vsrc = ksrc + 512;
#pragma unroll
      for (int i = 0; i < 4; ++i) vr[i] = *(const float4*)(vsrc + i * 4);
    }
    __syncthreads();
    float sa0[8] = {}, sa1[8] = {};
#pragma unroll
    for (int e0i = 0; e0i < 64; e0i += 4) {
      float4 qa = *(const float4*)&Qs[r0][e0i];
      float4 qb = *(const float4*)&Qs[r1][e0i];
#pragma unroll
      for (int j = 0; j < 8; ++j) {
        float4 kv = *(const float4*)&KVs[u + 8 * j][e0i];
        sa0[j] += qa.x * kv.x + qa.y * kv.y + qa.z * kv.z + qa.w * kv.w;
        sa1[j] += qb.x * kv.x + qb.y * kv.y + qb.z * kv.z + qb.w * kv.w;
      }
    }
    float pm0 = -1e30f, pm1 = -1e30f;
#pragma unroll
    for (int j = 0; j < 8; ++j) {
      pm0 = fmaxf(pm0, sa0[j]);
      pm1 = fmaxf(pm1, sa1[j]);
    }
    PM[r0][u] = pm0; PM[r1][u] = pm1;
    __syncthreads();
    // stage V into LDS (K no longer needed)
#pragma unroll
    for (int i = 0; i < 4; ++i) *(float4*)&KVs[lrow][lseg + i * 4] = vr[i];
    float mn0 = m0, mn1 = m1;
#pragma unroll
    for (int q = 0; q < 8; ++q) {
      mn0 = fmaxf(mn0, PM[r0][q]);
      mn1 = fmaxf(mn1, PM[r1][q]);
    }
    float f0 = __expf(m0 - mn0), f1 = __expf(m1 - mn1);
    float ps0 = 0.f, ps1 = 0.f;
#pragma unroll
    for (int j = 0; j < 8; ++j) {
      float ev0 = __expf(sa0[j] - mn0);
      float ev1 = __expf(sa1[j] - mn1);
      Ss[r0][u + 8 * j] = ev0;
      Ss[r1][u + 8 * j] = ev1;
      ps0 += ev0; ps1 += ev1;
    }
    PS[r0][u] = ps0; PS[r1][u] = ps1;
#pragma unroll
    for (int d = 0; d < 8; ++d) { acc0[d] *= f0; acc1[d] *= f1; }
    l0 *= f0; l1 *= f1; m0 = mn0; m1 = mn1;
    __syncthreads();
#pragma unroll
    for (int q = 0; q < 8; ++q) { l0 += PS[r0][q]; l1 += PS[r1][q]; }
#pragma unroll
    for (int kq = 0; kq < 64; kq += 4) {
      float4 p0 = *(const float4*)&Ss[r0][kq];
      float4 p1 = *(const float4*)&Ss[r1][kq];
      float p0a[4] = {p0.x, p0.y, p0.z, p0.w};
      float p1a[4] = {p1.x, p1.y, p1.z, p1.w};
#pragma unroll
      for (int kk = 0; kk < 4; ++kk) {
        float4 va = *(const float4*)&KVs[kq + kk][db];
        float4 vb = *(const float4*)&KVs[kq + kk][db + 4];
        float pw0 = p0a[kk], pw1 = p1a[kk];
        acc0[0] += pw0 * va.x; acc0[1] += pw0 * va.y;
        acc0[2] += pw0 * va.z; acc0[3] += pw0 * va.w;
        acc0[4] += pw0 * vb.x; acc0[5] += pw0 * vb.y;
        acc0[6] += pw0 * vb.z; acc0[7] += pw0 * vb.w;
        acc1[0] += pw1 * va.x; acc1[1] += pw1 * va.y;
        acc1[2] += pw1 * va.z; acc1[3] += pw1 * va.w;
        acc1[4] += pw1 * vb.x; acc1[5] += pw1 * vb.y;
        acc1[6] += pw1 * vb.z; acc1[7] += pw1 * vb.w;
      }
    }
  }
  float i0 = 1.f / l0, i1 = 1.f / l1;
  float* o0 = ob + (size_t)(bq + r0) * D_MODEL + h * DH + db;
  float* o1p = ob + (size_t)(bq + r1) * D_MODEL + h * DH + db;
  float4 w0, w1;
  w0.x = acc0[0] * i0; w0.y = acc0[1] * i0; w0.z = acc0[2] * i0; w0.w = acc0[3] * i0;
  w1.x = acc0[4] * i0; w1.y = acc0[5] * i0; w1.z = acc0[6] * i0; w1.w = acc0[7] * i0;
  *(float4*)o0 = w0; *(float4*)(o0 + 4) = w1;
  w0.x = acc1[0] * i1; w0.y = acc1[1] * i1; w0.z = acc1[2] * i1; w0.w = acc1[3] * i1;
  w1.x = acc1[4] * i1; w1.y = acc1[5] * i1; w1.z = acc1[6] * i1; w1.w = acc1[7] * i1;
  *(float4*)o1p = w0; *(float4*)(o1p + 4) = w1;
}

// ---------------- residual + layernorm ----------------
__global__ __launch_bounds__(128) void k_ln(const float* __restrict__ a,
                                            const float* __restrict__ r,
                                            const float* __restrict__ g,
                                            const float* __restrict__ b,
                                            float* __restrict__ out) {
  __shared__ float red[2];
  const int row = blockIdx.x, tid = threadIdx.x;
  const size_t off = (size_t)row * D_MODEL + tid * 4;
  float4 av = *(const float4*)(a + off);
  float4 rv = *(const float4*)(r + off);
  float v0 = av.x + rv.x, v1 = av.y + rv.y, v2 = av.z + rv.z, v3 = av.w + rv.w;
  float s = v0 + v1 + v2 + v3;
#pragma unroll
  for (int d = 1; d < 64; d <<= 1) s += __shfl_xor(s, d, 64);
  if ((tid & 63) == 0) red[tid >> 6] = s;
  __syncthreads();
  float mean = (red[0] + red[1]) * (1.f / 512.f);
  __syncthreads();
  float d0 = v0 - mean, d1 = v1 - mean, d2 = v2 - mean, d3 = v3 - mean;
  float sq = d0 * d0 + d1 * d1 + d2 * d2 + d3 * d3;
#pragma unroll
  for (int d = 1; d < 64; d <<= 1) sq += __shfl_xor(sq, d, 64);
  if ((tid & 63) == 0) red[tid >> 6] = sq;
  __syncthreads();
  float inv = rsqrtf((red[0] + red[1]) * (1.f / 512.f) + 1e-5f);
  float4 gv = *(const float4*)(g + tid * 4);
  float4 bv = *(const float4*)(b + tid * 4);
  float4 o;
  o.x = d0 * inv * gv.x + bv.x;
  o.y = d1 * inv * gv.y + bv.y;
  o.z = d2 * inv * gv.z + bv.z;
  o.w = d3 * inv * gv.w + bv.w;
  *(float4*)(out + off) = o;
}

// ---------------- emission scores feats = x2 * Wt^T + bt  [2048][32] ----------------
__global__ __launch_bounds__(256) void k_feats(const float* __restrict__ x2,
                                               const float* __restrict__ Wt,
                                               const float* __restrict__ bt,
                                               float* __restrict__ feats) {
  const int tid = threadIdx.x;
  const int s = blockIdx.x * 8 + (tid >> 5);
  const int l = tid & 31;
  const float* xr = x2 + (size_t)s * D_MODEL;
  const float* wr = Wt + (size_t)l * D_MODEL;
  float acc = 0.f;
#pragma unroll 8
  for (int k = 0; k < D_MODEL; k += 4) {
    float4 xv = *(const float4*)(xr + k);
    float4 wv = *(const float4*)(wr + k);
    acc += xv.x * wv.x + xv.y * wv.y + xv.z * wv.z + xv.w * wv.w;
  }
  feats[s * L_TAGS + l] = acc + bt[l];
}

// ---------------- Viterbi forward (serial, bitwise-exact f32), max only ----------------
__global__ __launch_bounds__(64) void k_vit_serial(const float* __restrict__ feats,
                                                   const float* __restrict__ T,
                                                   float* __restrict__ alphas,
                                                   float* __restrict__ out,
                                                   int* __restrict__ bestp) {
  const int l = threadIdx.x;
  const int n = l & 31, half = l >> 5;
  float Tr[16];
#pragma unroll
  for (int j = 0; j < 16; ++j) Tr[j] = T[n * 32 + half * 16 + j];
  float a = (n == START_TAG) ? 0.f : NEGV;
  if (l < 32) alphas[n] = a;
  float e0 = feats[n], e1 = feats[32 + n];
  for (int t = 0; t < S_LEN; ++t) {
    int tn = (t + 2 < S_LEN) ? (t + 2) : (S_LEN - 1);
    float e2 = feats[tn * 32 + n];
    float s[16];
#pragma unroll
    for (int j = 0; j < 16; ++j) s[j] = __shfl(a, half * 16 + j, 64) + Tr[j];
#pragma unroll
    for (int st = 1; st < 16; st <<= 1)
#pragma unroll
      for (int j = 0; j < 16; j += 2 * st) s[j] = fmaxf(s[j], s[j + st]);
    float m = fmaxf(s[0], __shfl_xor(s[0], 32, 64));
    a = m + e0;
    if (l < 32) alphas[(t + 1) * 32 + n] = a;
    e0 = e1; e1 = e2;
  }
  float term = a + T[STOP_TAG * 32 + n];
  float bv = term;
  int bi = n;
#pragma unroll
  for (int d = 1; d < 32; d <<= 1) {
    float ov = __shfl_xor(bv, d, 64);
    int oi = __shfl_xor(bi, d, 64);
    if (ov > bv || (ov == bv && oi < bi)) { bv = ov; bi = oi; }
  }
  if (l == 0) { out[0] = bv; *bestp = bi; }
}

// ---------------- backpointers (parallel, exact) ----------------
__global__ __launch_bounds__(256) void k_vit_bp(const float* __restrict__ alphas,
                                                const float* __restrict__ T,
                                                unsigned char* __restrict__ bp) {
  __shared__ float Ts[32][33];
  __shared__ float Al[8][32];
  const int tid = threadIdx.x;
  for (int i = tid; i < 1024; i += 256) Ts[i >> 5][i & 31] = T[i];
  const int t0 = blockIdx.x * 8;
  Al[tid >> 5][tid & 31] = alphas[t0 * 32 + tid];
  __syncthreads();
  const int tl = tid >> 5, n = tid & 31;
  float best = -3e38f;
  int bi = 0;
#pragma unroll
  for (int p = 0; p < 32; ++p) {
    float v = Al[tl][p] + Ts[n][p];
    if (v > best) { best = v; bi = p; }
  }
  bp[(size_t)(t0 + tl) * 32 + n] = (unsigned char)bi;
}

// ---------------- traceback: chunk candidate walks + pointer-doubling composition ----------------
__global__ __launch_bounds__(256) void k_vit_trace(const unsigned char* __restrict__ bp,
                                                   const int* __restrict__ bestp,
                                                   unsigned char* __restrict__ cand,
                                                   float* __restrict__ outp) {
  __shared__ unsigned char Amap[64][32];
  const int tid = threadIdx.x;
  int tg[8];
#pragma unroll
  for (int i = 0; i < 8; ++i) {
    int id = tid + 256 * i;
    tg[i] = id & 31;
    cand[(size_t)id * 32 + 31] = (unsigned char)tg[i];
  }
  for (int j = 31; j >= 1; --j) {
#pragma unroll
    for (int i = 0; i < 8; ++i) {
      int id = tid + 256 * i;
      tg[i] = bp[(size_t)((id >> 5) * 32 + j) * 32 + tg[i]];
      cand[(size_t)id * 32 + (j - 1)] = (unsigned char)tg[i];
    }
  }
#pragma unroll
  for (int i = 0; i < 8; ++i) {
    int id = tid + 256 * i;
    Amap[id >> 5][id & 31] = bp[(size_t)((id >> 5) * 32) * 32 + tg[i]];
  }
  __syncthreads();
  for (int d = 1; d < 64; d <<= 1) {
    unsigned char tmpv[8];
#pragma unroll
    for (int i = 0; i < 8; ++i) {
      int id = tid + 256 * i;
      int c = id >> 5, e = id & 31;
      tmpv[i] = (c + d < 64) ? Amap[c][Amap[c + d][e]] : Amap[c][e];
    }
    __syncthreads();
#pragma unroll
    for (int i = 0; i < 8; ++i) {
      int id = tid + 256 * i;
      Amap[id >> 5][id & 31] = tmpv[i];
    }
    __syncthreads();
  }
  const int best = *bestp;
#pragma unroll
  for (int i = 0; i < 8; ++i) {
    int t = tid + 256 * i;
    int c = t >> 5, j = t & 31;
    int et = (c == 63) ? best : Amap[c + 1][best];
    outp[1 + t] = (float)cand[(size_t)(c * 32 + et) * 32 + j];
  }
}

extern "C" void kernel_launch(void* const* d_in, const int* in_sizes, int n_in,
                              void* d_out, int out_size, void* d_ws, size_t ws_size,
                              hipStream_t stream) {
  (void)in_sizes; (void)n_in; (void)out_size; (void)ws_size;
  const int* sent = (const int*)d_in[0];
  const float* embed = (const float*)d_in[1];
  const float* Wqkv = (const float*)d_in[2];
  const float* bqkv = (const float*)d_in[3];
  const float* Wo = (const float*)d_in[4];
  const float* bo = (const float*)d_in[5];
  const float* g1 = (const float*)d_in[6];
  const float* b1n = (const float*)d_in[7];
  const float* W1 = (const float*)d_in[8];
  const float* b1f = (const float*)d_in[9];
  const float* W2 = (const float*)d_in[10];
  const float* b2f = (const float*)d_in[11];
  const float* g2 = (const float*)d_in[12];
  const float* b2n = (const float*)d_in[13];
  const float* Wt = (const float*)d_in[14];
  const float* bt = (const float*)d_in[15];
  const float* T = (const float*)d_in[16];
  float* out = (float*)d_out;

  float* ws = (float*)d_ws;
  const size_t M1 = 1u << 20;  // 1M floats = 4MB
  float* x = ws;               // [2048][512]
  float* qkvb = ws + M1;       // [2048][1536]
  float* ob = ws + 4 * M1;     // [2048][512]
  float* yb = ws + 5 * M1;     // [2048][512]
  float* x1 = ws + 6 * M1;     // [2048][512]
  float* ffb = ws;             // [2048][2048]  (aliases x+qkvb, dead by then)
  float* zb = ws + 4 * M1;     // aliases ob
  float* x2 = ws + 5 * M1;     // aliases yb
  float* feats = ws + 7 * M1;  // [2048][32]
  float* alphas = feats + 2048 * 32;            // [2049][32]
  int* bestp = (int*)(alphas + 2049 * 32 + 32);
  unsigned char* bp = (unsigned char*)(bestp + 32);  // [2048][32] u8
  unsigned char* cand = bp + 2048 * 32;              // [2048][32] u8

  k_embed<<<dim3(2048), dim3(128), 0, stream>>>(sent, embed, x);
  k_gemm128<false><<<dim3(12, 16), dim3(256), 0, stream>>>(x, Wqkv, bqkv, qkvb, 2048, 1536, 512);
  k_attn<<<dim3(32, 8), dim3(256), 0, stream>>>(qkvb, ob);
  k_gemm64<false><<<dim3(8, 32), dim3(256), 0, stream>>>(ob, Wo, bo, yb, 2048, 512, 512);
  k_ln<<<dim3(2048), dim3(128), 0, stream>>>(x, yb, g1, b1n, x1);
  k_gemm128<true><<<dim3(16, 16), dim3(256), 0, stream>>>(x1, W1, b1f, ffb, 2048, 2048, 512);
  k_gemm64<false><<<dim3(8, 32), dim3(256), 0, stream>>>(ffb, W2, b2f, zb, 2048, 512, 2048);
  k_ln<<<dim3(2048), dim3(128), 0, stream>>>(x1, zb, g2, b2n, x2);
  k_feats<<<dim3(256), dim3(256), 0, stream>>>(x2, Wt, bt, feats);
  k_vit_serial<<<dim3(1), dim3(64), 0, stream>>>(feats, T, alphas, out, bestp);
  k_vit_bp<<<dim3(256), dim3(256), 0, stream>>>(alphas, T, bp);
  k_vit_trace<<<dim3(1), dim3(256), 0, stream>>>(bp, bestp, cand, out);
}

// Round 3
// 1067.451 us; speedup vs baseline: 1.2496x; 1.2496x over previous
//
#include <hip/hip_runtime.h>
#include <cstddef>

#define S_LEN 2048
#define D_MODEL 512
#define NHEAD 8
#define DH 64
#define FF_DIM 2048
#define L_TAGS 32
#define START_TAG 30
#define STOP_TAG 31
#define NEGV (-10000.0f)

typedef unsigned int uint2v __attribute__((ext_vector_type(2)));

// ---------------- embedding gather ----------------
__global__ __launch_bounds__(128) void k_embed(const int* __restrict__ sent,
                                               const float* __restrict__ embed,
                                               float* __restrict__ x) {
  int s = blockIdx.x;
  int d = threadIdx.x * 4;
  size_t idx = (size_t)sent[s] * D_MODEL + d;
  *(float4*)(x + (size_t)s * D_MODEL + d) = *(const float4*)(embed + idx);
}

// ---------------- GEMM C[M][N] = A[M][K] * B[N][K]^T + bias, 128x128 tile ----------------
template <bool RELU>
__global__ __launch_bounds__(256) void k_gemm128(const float* __restrict__ A,
                                                 const float* __restrict__ B,
                                                 const float* __restrict__ bias,
                                                 float* __restrict__ C,
                                                 int M, int N, int K) {
  __shared__ float As[16][132];
  __shared__ float Bs[16][132];
  const int tid = threadIdx.x;
  const int bm = blockIdx.y * 128, bn = blockIdx.x * 128;
  const int lrow = tid >> 1;
  const int lks = (tid & 1) * 8;
  const int row0 = (tid >> 4) * 8;
  const int col0 = (tid & 15) * 8;
  float acc[8][8] = {};
  for (int k0 = 0; k0 < K; k0 += 16) {
    float4 a0 = *(const float4*)(A + (size_t)(bm + lrow) * K + k0 + lks);
    float4 a1 = *(const float4*)(A + (size_t)(bm + lrow) * K + k0 + lks + 4);
    float4 b0 = *(const float4*)(B + (size_t)(bn + lrow) * K + k0 + lks);
    float4 b1 = *(const float4*)(B + (size_t)(bn + lrow) * K + k0 + lks + 4);
    __syncthreads();
    As[lks + 0][lrow] = a0.x; As[lks + 1][lrow] = a0.y;
    As[lks + 2][lrow] = a0.z; As[lks + 3][lrow] = a0.w;
    As[lks + 4][lrow] = a1.x; As[lks + 5][lrow] = a1.y;
    As[lks + 6][lrow] = a1.z; As[lks + 7][lrow] = a1.w;
    Bs[lks + 0][lrow] = b0.x; Bs[lks + 1][lrow] = b0.y;
    Bs[lks + 2][lrow] = b0.z; Bs[lks + 3][lrow] = b0.w;
    Bs[lks + 4][lrow] = b1.x; Bs[lks + 5][lrow] = b1.y;
    Bs[lks + 6][lrow] = b1.z; Bs[lks + 7][lrow] = b1.w;
    __syncthreads();
#pragma unroll
    for (int kk = 0; kk < 16; ++kk) {
      float4 av0 = *(const float4*)&As[kk][row0];
      float4 av1 = *(const float4*)&As[kk][row0 + 4];
      float4 bv0 = *(const float4*)&Bs[kk][col0];
      float4 bv1 = *(const float4*)&Bs[kk][col0 + 4];
      float ar[8] = {av0.x, av0.y, av0.z, av0.w, av1.x, av1.y, av1.z, av1.w};
      float br[8] = {bv0.x, bv0.y, bv0.z, bv0.w, bv1.x, bv1.y, bv1.z, bv1.w};
#pragma unroll
      for (int i = 0; i < 8; ++i)
#pragma unroll
        for (int j = 0; j < 8; ++j) acc[i][j] += ar[i] * br[j];
    }
  }
#pragma unroll
  for (int i = 0; i < 8; ++i) {
    int r = bm + row0 + i;
    float4 o0, o1;
    o0.x = acc[i][0] + bias[bn + col0 + 0];
    o0.y = acc[i][1] + bias[bn + col0 + 1];
    o0.z = acc[i][2] + bias[bn + col0 + 2];
    o0.w = acc[i][3] + bias[bn + col0 + 3];
    o1.x = acc[i][4] + bias[bn + col0 + 4];
    o1.y = acc[i][5] + bias[bn + col0 + 5];
    o1.z = acc[i][6] + bias[bn + col0 + 6];
    o1.w = acc[i][7] + bias[bn + col0 + 7];
    if (RELU) {
      o0.x = fmaxf(o0.x, 0.f); o0.y = fmaxf(o0.y, 0.f);
      o0.z = fmaxf(o0.z, 0.f); o0.w = fmaxf(o0.w, 0.f);
      o1.x = fmaxf(o1.x, 0.f); o1.y = fmaxf(o1.y, 0.f);
      o1.z = fmaxf(o1.z, 0.f); o1.w = fmaxf(o1.w, 0.f);
    }
    *(float4*)(C + (size_t)r * N + bn + col0) = o0;
    *(float4*)(C + (size_t)r * N + bn + col0 + 4) = o1;
  }
}

// ---------------- GEMM 64x64 tile (for N=512 cases) ----------------
template <bool RELU>
__global__ __launch_bounds__(256) void k_gemm64(const float* __restrict__ A,
                                                const float* __restrict__ B,
                                                const float* __restrict__ bias,
                                                float* __restrict__ C,
                                                int M, int N, int K) {
  __shared__ float As[16][68];
  __shared__ float Bs[16][68];
  const int tid = threadIdx.x;
  const int bm = blockIdx.y * 64, bn = blockIdx.x * 64;
  const int tx = tid & 15, ty = tid >> 4;
  const int lr = tid >> 2, lk = (tid & 3) * 4;
  float acc[4][4] = {};
  for (int k0 = 0; k0 < K; k0 += 16) {
    float4 a4 = *(const float4*)(A + (size_t)(bm + lr) * K + k0 + lk);
    float4 b4 = *(const float4*)(B + (size_t)(bn + lr) * K + k0 + lk);
    __syncthreads();
    As[lk + 0][lr] = a4.x; As[lk + 1][lr] = a4.y;
    As[lk + 2][lr] = a4.z; As[lk + 3][lr] = a4.w;
    Bs[lk + 0][lr] = b4.x; Bs[lk + 1][lr] = b4.y;
    Bs[lk + 2][lr] = b4.z; Bs[lk + 3][lr] = b4.w;
    __syncthreads();
#pragma unroll
    for (int kk = 0; kk < 16; ++kk) {
      float4 av = *(const float4*)&As[kk][ty * 4];
      float4 bv = *(const float4*)&Bs[kk][tx * 4];
      float ar[4] = {av.x, av.y, av.z, av.w};
      float br[4] = {bv.x, bv.y, bv.z, bv.w};
#pragma unroll
      for (int i = 0; i < 4; ++i)
#pragma unroll
        for (int j = 0; j < 4; ++j) acc[i][j] += ar[i] * br[j];
    }
  }
#pragma unroll
  for (int i = 0; i < 4; ++i) {
    float4 o;
    o.x = acc[i][0] + bias[bn + tx * 4 + 0];
    o.y = acc[i][1] + bias[bn + tx * 4 + 1];
    o.z = acc[i][2] + bias[bn + tx * 4 + 2];
    o.w = acc[i][3] + bias[bn + tx * 4 + 3];
    if (RELU) {
      o.x = fmaxf(o.x, 0.f); o.y = fmaxf(o.y, 0.f);
      o.z = fmaxf(o.z, 0.f); o.w = fmaxf(o.w, 0.f);
    }
    *(float4*)(C + (size_t)(bm + ty * 4 + i) * N + bn + tx * 4) = o;
  }
}

// ---------------- fused attention (per head, 64-query tiles, online softmax) ----------------
__global__ __launch_bounds__(256) void k_attn(const float* __restrict__ qkv,
                                              float* __restrict__ ob) {
  __shared__ float Qs[64][68];
  __shared__ float KVs[64][68];
  __shared__ float Ss[64][68];
  __shared__ float PM[64][8];
  __shared__ float PS[64][8];
  const int tid = threadIdx.x;
  const int bq = blockIdx.x * 64;
  const int h = blockIdx.y;
  const int lrow = tid >> 2, lseg = (tid & 3) * 16;
  {
    const float* src = qkv + (size_t)(bq + lrow) * 1536 + h * DH + lseg;
#pragma unroll
    for (int i = 0; i < 4; ++i) {
      float4 v = *(const float4*)(src + i * 4);
      v.x *= 0.125f; v.y *= 0.125f; v.z *= 0.125f; v.w *= 0.125f;
      *(float4*)&Qs[lrow][lseg + i * 4] = v;
    }
  }
  const int u = tid & 7, rp = tid >> 3;
  const int r0 = rp * 2, r1 = r0 + 1, db = u * 8;
  float m0 = -1e30f, m1 = -1e30f, l0 = 0.f, l1 = 0.f;
  float acc0[8] = {}, acc1[8] = {};
  for (int kt = 0; kt < 32; ++kt) {
    __syncthreads();
    float4 vr[4];
    {
      const float* ksrc = qkv + (size_t)(kt * 64 + lrow) * 1536 + 512 + h * DH + lseg;
#pragma unroll
      for (int i = 0; i < 4; ++i)
        *(float4*)&KVs[lrow][lseg + i * 4] = *(const float4*)(ksrc + i * 4);
      const float* vsrc = ksrc + 512;
#pragma unroll
      for (int i = 0; i < 4; ++i) vr[i] = *(const float4*)(vsrc + i * 4);
    }
    __syncthreads();
    float sa0[8] = {}, sa1[8] = {};
#pragma unroll
    for (int e0i = 0; e0i < 64; e0i += 4) {
      float4 qa = *(const float4*)&Qs[r0][e0i];
      float4 qb = *(const float4*)&Qs[r1][e0i];
#pragma unroll
      for (int j = 0; j < 8; ++j) {
        float4 kv = *(const float4*)&KVs[u + 8 * j][e0i];
        sa0[j] += qa.x * kv.x + qa.y * kv.y + qa.z * kv.z + qa.w * kv.w;
        sa1[j] += qb.x * kv.x + qb.y * kv.y + qb.z * kv.z + qb.w * kv.w;
      }
    }
    float pm0 = -1e30f, pm1 = -1e30f;
#pragma unroll
    for (int j = 0; j < 8; ++j) {
      pm0 = fmaxf(pm0, sa0[j]);
      pm1 = fmaxf(pm1, sa1[j]);
    }
    PM[r0][u] = pm0; PM[r1][u] = pm1;
    __syncthreads();
    // stage V into LDS (K no longer needed)
#pragma unroll
    for (int i = 0; i < 4; ++i) *(float4*)&KVs[lrow][lseg + i * 4] = vr[i];
    float mn0 = m0, mn1 = m1;
#pragma unroll
    for (int q = 0; q < 8; ++q) {
      mn0 = fmaxf(mn0, PM[r0][q]);
      mn1 = fmaxf(mn1, PM[r1][q]);
    }
    float f0 = __expf(m0 - mn0), f1 = __expf(m1 - mn1);
    float ps0 = 0.f, ps1 = 0.f;
#pragma unroll
    for (int j = 0; j < 8; ++j) {
      float ev0 = __expf(sa0[j] - mn0);
      float ev1 = __expf(sa1[j] - mn1);
      Ss[r0][u + 8 * j] = ev0;
      Ss[r1][u + 8 * j] = ev1;
      ps0 += ev0; ps1 += ev1;
    }
    PS[r0][u] = ps0; PS[r1][u] = ps1;
#pragma unroll
    for (int d = 0; d < 8; ++d) { acc0[d] *= f0; acc1[d] *= f1; }
    l0 *= f0; l1 *= f1; m0 = mn0; m1 = mn1;
    __syncthreads();
#pragma unroll
    for (int q = 0; q < 8; ++q) { l0 += PS[r0][q]; l1 += PS[r1][q]; }
#pragma unroll
    for (int kq = 0; kq < 64; kq += 4) {
      float4 p0 = *(const float4*)&Ss[r0][kq];
      float4 p1 = *(const float4*)&Ss[r1][kq];
      float p0a[4] = {p0.x, p0.y, p0.z, p0.w};
      float p1a[4] = {p1.x, p1.y, p1.z, p1.w};
#pragma unroll
      for (int kk = 0; kk < 4; ++kk) {
        float4 va = *(const float4*)&KVs[kq + kk][db];
        float4 vb = *(const float4*)&KVs[kq + kk][db + 4];
        float pw0 = p0a[kk], pw1 = p1a[kk];
        acc0[0] += pw0 * va.x; acc0[1] += pw0 * va.y;
        acc0[2] += pw0 * va.z; acc0[3] += pw0 * va.w;
        acc0[4] += pw0 * vb.x; acc0[5] += pw0 * vb.y;
        acc0[6] += pw0 * vb.z; acc0[7] += pw0 * vb.w;
        acc1[0] += pw1 * va.x; acc1[1] += pw1 * va.y;
        acc1[2] += pw1 * va.z; acc1[3] += pw1 * va.w;
        acc1[4] += pw1 * vb.x; acc1[5] += pw1 * vb.y;
        acc1[6] += pw1 * vb.z; acc1[7] += pw1 * vb.w;
      }
    }
  }
  float i0 = 1.f / l0, i1 = 1.f / l1;
  float* o0 = ob + (size_t)(bq + r0) * D_MODEL + h * DH + db;
  float* o1p = ob + (size_t)(bq + r1) * D_MODEL + h * DH + db;
  float4 w0, w1;
  w0.x = acc0[0] * i0; w0.y = acc0[1] * i0; w0.z = acc0[2] * i0; w0.w = acc0[3] * i0;
  w1.x = acc0[4] * i0; w1.y = acc0[5] * i0; w1.z = acc0[6] * i0; w1.w = acc0[7] * i0;
  *(float4*)o0 = w0; *(float4*)(o0 + 4) = w1;
  w0.x = acc1[0] * i1; w0.y = acc1[1] * i1; w0.z = acc1[2] * i1; w0.w = acc1[3] * i1;
  w1.x = acc1[4] * i1; w1.y = acc1[5] * i1; w1.z = acc1[6] * i1; w1.w = acc1[7] * i1;
  *(float4*)o1p = w0; *(float4*)(o1p + 4) = w1;
}

// ---------------- residual + layernorm ----------------
__global__ __launch_bounds__(128) void k_ln(const float* __restrict__ a,
                                            const float* __restrict__ r,
                                            const float* __restrict__ g,
                                            const float* __restrict__ b,
                                            float* __restrict__ out) {
  __shared__ float red[2];
  const int row = blockIdx.x, tid = threadIdx.x;
  const size_t off = (size_t)row * D_MODEL + tid * 4;
  float4 av = *(const float4*)(a + off);
  float4 rv = *(const float4*)(r + off);
  float v0 = av.x + rv.x, v1 = av.y + rv.y, v2 = av.z + rv.z, v3 = av.w + rv.w;
  float s = v0 + v1 + v2 + v3;
#pragma unroll
  for (int d = 1; d < 64; d <<= 1) s += __shfl_xor(s, d, 64);
  if ((tid & 63) == 0) red[tid >> 6] = s;
  __syncthreads();
  float mean = (red[0] + red[1]) * (1.f / 512.f);
  __syncthreads();
  float d0 = v0 - mean, d1 = v1 - mean, d2 = v2 - mean, d3 = v3 - mean;
  float sq = d0 * d0 + d1 * d1 + d2 * d2 + d3 * d3;
#pragma unroll
  for (int d = 1; d < 64; d <<= 1) sq += __shfl_xor(sq, d, 64);
  if ((tid & 63) == 0) red[tid >> 6] = sq;
  __syncthreads();
  float inv = rsqrtf((red[0] + red[1]) * (1.f / 512.f) + 1e-5f);
  float4 gv = *(const float4*)(g + tid * 4);
  float4 bv = *(const float4*)(b + tid * 4);
  float4 o;
  o.x = d0 * inv * gv.x + bv.x;
  o.y = d1 * inv * gv.y + bv.y;
  o.z = d2 * inv * gv.z + bv.z;
  o.w = d3 * inv * gv.w + bv.w;
  *(float4*)(out + off) = o;
}

// ---------------- emission scores feats = x2 * Wt^T + bt  [2048][32] ----------------
__global__ __launch_bounds__(256) void k_feats(const float* __restrict__ x2,
                                               const float* __restrict__ Wt,
                                               const float* __restrict__ bt,
                                               float* __restrict__ feats) {
  const int tid = threadIdx.x;
  const int s = blockIdx.x * 8 + (tid >> 5);
  const int l = tid & 31;
  const float* xr = x2 + (size_t)s * D_MODEL;
  const float* wr = Wt + (size_t)l * D_MODEL;
  float acc = 0.f;
#pragma unroll 8
  for (int k = 0; k < D_MODEL; k += 4) {
    float4 xv = *(const float4*)(xr + k);
    float4 wv = *(const float4*)(wr + k);
    acc += xv.x * wv.x + xv.y * wv.y + xv.z * wv.z + xv.w * wv.w;
  }
  feats[s * L_TAGS + l] = acc + bt[l];
}

// ---------------- Viterbi forward (serial, bitwise-exact f32), max only ----------------
// lane l: tag n = l&31, half = l>>5 reduces prev tags [16*half, 16*half+15].
// cross-half combine via __builtin_amdgcn_permlane32_swap (compiler-managed
// two-register semantics; inline-asm version aliased hi/lo into one reg).
__global__ __launch_bounds__(64) void k_vit_serial(const float* __restrict__ feats,
                                                   const float* __restrict__ T,
                                                   float* __restrict__ alphas,
                                                   float* __restrict__ out,
                                                   int* __restrict__ bestp) {
  const int l = threadIdx.x;
  const int n = l & 31, half = l >> 5;
  float Tr[16];
#pragma unroll
  for (int j = 0; j < 16; ++j) Tr[j] = T[n * 32 + half * 16 + j];
  int adr[16];  // loop-invariant bpermute byte addresses (src lane half*16+j)
#pragma unroll
  for (int j = 0; j < 16; ++j) adr[j] = (half * 16 + j) * 4;
  float a = (n == START_TAG) ? 0.f : NEGV;
  alphas[n] = a;  // both halves write identical value — benign
  float e0 = feats[n], e1 = feats[32 + n], e2 = feats[64 + n], e3 = feats[96 + n];
  const float* fp = feats + 128 + n;   // prefetch 4 ahead
  float* ap = alphas + 32 + n;
  for (int t = 0; t < S_LEN; t += 2) {
    // prefetch rows t+4, t+5 (tail reads spill into alphas buffer — allocated,
    // values discarded: harmless)
    float eA = fp[0], eB = fp[32];
    fp += 64;
#pragma unroll
    for (int u = 0; u < 2; ++u) {
      float g[16];
#pragma unroll
      for (int j = 0; j < 16; ++j)
        g[j] = __int_as_float(__builtin_amdgcn_ds_bpermute(adr[j], __float_as_int(a))) + Tr[j];
#pragma unroll
      for (int st = 1; st < 16; st <<= 1)
#pragma unroll
        for (int j = 0; j < 16; j += 2 * st) g[j] = fmaxf(g[j], g[j + st]);
      // cross-half max: r[0][lane]=g[lane&31], r[1][lane]=g[32|(lane&31)]
      uint2v r = __builtin_amdgcn_permlane32_swap(__float_as_uint(g[0]),
                                                  __float_as_uint(g[0]),
                                                  false, false);
      a = fmaxf(__uint_as_float(r[0]), __uint_as_float(r[1])) + (u == 0 ? e0 : e1);
      ap[u * 32] = a;
    }
    ap += 64;
    e0 = e2; e1 = e3; e2 = eA; e3 = eB;
  }
  float term = a + T[STOP_TAG * 32 + n];
  float bv = term;
  int bi = n;
#pragma unroll
  for (int d = 1; d < 32; d <<= 1) {
    float ov = __shfl_xor(bv, d, 64);
    int oi = __shfl_xor(bi, d, 64);
    if (ov > bv || (ov == bv && oi < bi)) { bv = ov; bi = oi; }
  }
  if (l == 0) { out[0] = bv; *bestp = bi; }
}

// ---------------- backpointers (parallel, exact) ----------------
__global__ __launch_bounds__(256) void k_vit_bp(const float* __restrict__ alphas,
                                                const float* __restrict__ T,
                                                unsigned char* __restrict__ bp) {
  __shared__ float Ts[32][33];
  __shared__ float Al[8][32];
  const int tid = threadIdx.x;
  for (int i = tid; i < 1024; i += 256) Ts[i >> 5][i & 31] = T[i];
  const int t0 = blockIdx.x * 8;
  Al[tid >> 5][tid & 31] = alphas[t0 * 32 + tid];
  __syncthreads();
  const int tl = tid >> 5, n = tid & 31;
  float best = -3e38f;
  int bi = 0;
#pragma unroll
  for (int p = 0; p < 32; ++p) {
    float v = Al[tl][p] + Ts[n][p];
    if (v > best) { best = v; bi = p; }
  }
  bp[(size_t)(t0 + tl) * 32 + n] = (unsigned char)bi;
}

// ---------------- traceback: chunk candidate walks + pointer-doubling composition ----------------
__global__ __launch_bounds__(256) void k_vit_trace(const unsigned char* __restrict__ bp,
                                                   const int* __restrict__ bestp,
                                                   unsigned char* __restrict__ cand,
                                                   float* __restrict__ outp) {
  __shared__ unsigned char Amap[64][32];
  const int tid = threadIdx.x;
  int tg[8];
#pragma unroll
  for (int i = 0; i < 8; ++i) {
    int id = tid + 256 * i;
    tg[i] = id & 31;
    cand[(size_t)id * 32 + 31] = (unsigned char)tg[i];
  }
  for (int j = 31; j >= 1; --j) {
#pragma unroll
    for (int i = 0; i < 8; ++i) {
      int id = tid + 256 * i;
      tg[i] = bp[(size_t)((id >> 5) * 32 + j) * 32 + tg[i]];
      cand[(size_t)id * 32 + (j - 1)] = (unsigned char)tg[i];
    }
  }
#pragma unroll
  for (int i = 0; i < 8; ++i) {
    int id = tid + 256 * i;
    Amap[id >> 5][id & 31] = bp[(size_t)((id >> 5) * 32) * 32 + tg[i]];
  }
  __syncthreads();
  for (int d = 1; d < 64; d <<= 1) {
    unsigned char tmpv[8];
#pragma unroll
    for (int i = 0; i < 8; ++i) {
      int id = tid + 256 * i;
      int c = id >> 5, e = id & 31;
      tmpv[i] = (c + d < 64) ? Amap[c][Amap[c + d][e]] : Amap[c][e];
    }
    __syncthreads();
#pragma unroll
    for (int i = 0; i < 8; ++i) {
      int id = tid + 256 * i;
      Amap[id >> 5][id & 31] = tmpv[i];
    }
    __syncthreads();
  }
  const int best = *bestp;
#pragma unroll
  for (int i = 0; i < 8; ++i) {
    int t = tid + 256 * i;
    int c = t >> 5, j = t & 31;
    int et = (c == 63) ? best : Amap[c + 1][best];
    outp[1 + t] = (float)cand[(size_t)(c * 32 + et) * 32 + j];
  }
}

extern "C" void kernel_launch(void* const* d_in, const int* in_sizes, int n_in,
                              void* d_out, int out_size, void* d_ws, size_t ws_size,
                              hipStream_t stream) {
  (void)in_sizes; (void)n_in; (void)out_size; (void)ws_size;
  const int* sent = (const int*)d_in[0];
  const float* embed = (const float*)d_in[1];
  const float* Wqkv = (const float*)d_in[2];
  const float* bqkv = (const float*)d_in[3];
  const float* Wo = (const float*)d_in[4];
  const float* bo = (const float*)d_in[5];
  const float* g1 = (const float*)d_in[6];
  const float* b1n = (const float*)d_in[7];
  const float* W1 = (const float*)d_in[8];
  const float* b1f = (const float*)d_in[9];
  const float* W2 = (const float*)d_in[10];
  const float* b2f = (const float*)d_in[11];
  const float* g2 = (const float*)d_in[12];
  const float* b2n = (const float*)d_in[13];
  const float* Wt = (const float*)d_in[14];
  const float* bt = (const float*)d_in[15];
  const float* T = (const float*)d_in[16];
  float* out = (float*)d_out;

  float* ws = (float*)d_ws;
  const size_t M1 = 1u << 20;  // 1M floats = 4MB
  float* x = ws;               // [2048][512]
  float* qkvb = ws + M1;       // [2048][1536]
  float* ob = ws + 4 * M1;     // [2048][512]
  float* yb = ws + 5 * M1;     // [2048][512]
  float* x1 = ws + 6 * M1;     // [2048][512]
  float* ffb = ws;             // [2048][2048]  (aliases x+qkvb, dead by then)
  float* zb = ws + 4 * M1;     // aliases ob
  float* x2 = ws + 5 * M1;     // aliases yb
  float* feats = ws + 7 * M1;  // [2048][32]
  float* alphas = feats + 2048 * 32;            // [2049][32]
  int* bestp = (int*)(alphas + 2049 * 32 + 32);
  unsigned char* bp = (unsigned char*)(bestp + 32);  // [2048][32] u8
  unsigned char* cand = bp + 2048 * 32;              // [2048][32] u8

  k_embed<<<dim3(2048), dim3(128), 0, stream>>>(sent, embed, x);
  k_gemm128<false><<<dim3(12, 16), dim3(256), 0, stream>>>(x, Wqkv, bqkv, qkvb, 2048, 1536, 512);
  k_attn<<<dim3(32, 8), dim3(256), 0, stream>>>(qkvb, ob);
  k_gemm64<false><<<dim3(8, 32), dim3(256), 0, stream>>>(ob, Wo, bo, yb, 2048, 512, 512);
  k_ln<<<dim3(2048), dim3(128), 0, stream>>>(x, yb, g1, b1n, x1);
  k_gemm128<true><<<dim3(16, 16), dim3(256), 0, stream>>>(x1, W1, b1f, ffb, 2048, 2048, 512);
  k_gemm64<false><<<dim3(8, 32), dim3(256), 0, stream>>>(ffb, W2, b2f, zb, 2048, 512, 2048);
  k_ln<<<dim3(2048), dim3(128), 0, stream>>>(x1, zb, g2, b2n, x2);
  k_feats<<<dim3(256), dim3(256), 0, stream>>>(x2, Wt, bt, feats);
  k_vit_serial<<<dim3(1), dim3(64), 0, stream>>>(feats, T, alphas, out, bestp);
  k_vit_bp<<<dim3(256), dim3(256), 0, stream>>>(alphas, T, bp);
  k_vit_trace<<<dim3(1), dim3(256), 0, stream>>>(bp, bestp, cand, out);
}

// Round 4
// 914.661 us; speedup vs baseline: 1.4584x; 1.1670x over previous
//
#include <hip/hip_runtime.h>
#include <cstddef>

#define S_LEN 2048
#define D_MODEL 512
#define NHEAD 8
#define DH 64
#define FF_DIM 2048
#define L_TAGS 32
#define START_TAG 30
#define STOP_TAG 31
#define NEGV (-10000.0f)

typedef unsigned int uint2v __attribute__((ext_vector_type(2)));

__device__ __forceinline__ float max3f(float a, float b, float c) {
  float d;
  asm("v_max3_f32 %0, %1, %2, %3" : "=v"(d) : "v"(a), "v"(b), "v"(c));
  return d;
}

// ---------------- embedding gather ----------------
__global__ __launch_bounds__(128) void k_embed(const int* __restrict__ sent,
                                               const float* __restrict__ embed,
                                               float* __restrict__ x) {
  int s = blockIdx.x;
  int d = threadIdx.x * 4;
  size_t idx = (size_t)sent[s] * D_MODEL + d;
  *(float4*)(x + (size_t)s * D_MODEL + d) = *(const float4*)(embed + idx);
}

// ---------------- GEMM C[M][N] = A[M][K] * B[N][K]^T + bias, 128x128 tile ----------------
template <bool RELU>
__global__ __launch_bounds__(256) void k_gemm128(const float* __restrict__ A,
                                                 const float* __restrict__ B,
                                                 const float* __restrict__ bias,
                                                 float* __restrict__ C,
                                                 int M, int N, int K) {
  __shared__ float As[16][132];
  __shared__ float Bs[16][132];
  const int tid = threadIdx.x;
  const int bm = blockIdx.y * 128, bn = blockIdx.x * 128;
  const int lrow = tid >> 1;
  const int lks = (tid & 1) * 8;
  const int row0 = (tid >> 4) * 8;
  const int col0 = (tid & 15) * 8;
  float acc[8][8] = {};
  for (int k0 = 0; k0 < K; k0 += 16) {
    float4 a0 = *(const float4*)(A + (size_t)(bm + lrow) * K + k0 + lks);
    float4 a1 = *(const float4*)(A + (size_t)(bm + lrow) * K + k0 + lks + 4);
    float4 b0 = *(const float4*)(B + (size_t)(bn + lrow) * K + k0 + lks);
    float4 b1 = *(const float4*)(B + (size_t)(bn + lrow) * K + k0 + lks + 4);
    __syncthreads();
    As[lks + 0][lrow] = a0.x; As[lks + 1][lrow] = a0.y;
    As[lks + 2][lrow] = a0.z; As[lks + 3][lrow] = a0.w;
    As[lks + 4][lrow] = a1.x; As[lks + 5][lrow] = a1.y;
    As[lks + 6][lrow] = a1.z; As[lks + 7][lrow] = a1.w;
    Bs[lks + 0][lrow] = b0.x; Bs[lks + 1][lrow] = b0.y;
    Bs[lks + 2][lrow] = b0.z; Bs[lks + 3][lrow] = b0.w;
    Bs[lks + 4][lrow] = b1.x; Bs[lks + 5][lrow] = b1.y;
    Bs[lks + 6][lrow] = b1.z; Bs[lks + 7][lrow] = b1.w;
    __syncthreads();
#pragma unroll
    for (int kk = 0; kk < 16; ++kk) {
      float4 av0 = *(const float4*)&As[kk][row0];
      float4 av1 = *(const float4*)&As[kk][row0 + 4];
      float4 bv0 = *(const float4*)&Bs[kk][col0];
      float4 bv1 = *(const float4*)&Bs[kk][col0 + 4];
      float ar[8] = {av0.x, av0.y, av0.z, av0.w, av1.x, av1.y, av1.z, av1.w};
      float br[8] = {bv0.x, bv0.y, bv0.z, bv0.w, bv1.x, bv1.y, bv1.z, bv1.w};
#pragma unroll
      for (int i = 0; i < 8; ++i)
#pragma unroll
        for (int j = 0; j < 8; ++j) acc[i][j] += ar[i] * br[j];
    }
  }
#pragma unroll
  for (int i = 0; i < 8; ++i) {
    int r = bm + row0 + i;
    float4 o0, o1;
    o0.x = acc[i][0] + bias[bn + col0 + 0];
    o0.y = acc[i][1] + bias[bn + col0 + 1];
    o0.z = acc[i][2] + bias[bn + col0 + 2];
    o0.w = acc[i][3] + bias[bn + col0 + 3];
    o1.x = acc[i][4] + bias[bn + col0 + 4];
    o1.y = acc[i][5] + bias[bn + col0 + 5];
    o1.z = acc[i][6] + bias[bn + col0 + 6];
    o1.w = acc[i][7] + bias[bn + col0 + 7];
    if (RELU) {
      o0.x = fmaxf(o0.x, 0.f); o0.y = fmaxf(o0.y, 0.f);
      o0.z = fmaxf(o0.z, 0.f); o0.w = fmaxf(o0.w, 0.f);
      o1.x = fmaxf(o1.x, 0.f); o1.y = fmaxf(o1.y, 0.f);
      o1.z = fmaxf(o1.z, 0.f); o1.w = fmaxf(o1.w, 0.f);
    }
    *(float4*)(C + (size_t)r * N + bn + col0) = o0;
    *(float4*)(C + (size_t)r * N + bn + col0 + 4) = o1;
  }
}

// ---------------- GEMM 64x64 tile (for N=512 cases) ----------------
template <bool RELU>
__global__ __launch_bounds__(256) void k_gemm64(const float* __restrict__ A,
                                                const float* __restrict__ B,
                                                const float* __restrict__ bias,
                                                float* __restrict__ C,
                                                int M, int N, int K) {
  __shared__ float As[16][68];
  __shared__ float Bs[16][68];
  const int tid = threadIdx.x;
  const int bm = blockIdx.y * 64, bn = blockIdx.x * 64;
  const int tx = tid & 15, ty = tid >> 4;
  const int lr = tid >> 2, lk = (tid & 3) * 4;
  float acc[4][4] = {};
  for (int k0 = 0; k0 < K; k0 += 16) {
    float4 a4 = *(const float4*)(A + (size_t)(bm + lr) * K + k0 + lk);
    float4 b4 = *(const float4*)(B + (size_t)(bn + lr) * K + k0 + lk);
    __syncthreads();
    As[lk + 0][lr] = a4.x; As[lk + 1][lr] = a4.y;
    As[lk + 2][lr] = a4.z; As[lk + 3][lr] = a4.w;
    Bs[lk + 0][lr] = b4.x; Bs[lk + 1][lr] = b4.y;
    Bs[lk + 2][lr] = b4.z; Bs[lk + 3][lr] = b4.w;
    __syncthreads();
#pragma unroll
    for (int kk = 0; kk < 16; ++kk) {
      float4 av = *(const float4*)&As[kk][ty * 4];
      float4 bv = *(const float4*)&Bs[kk][tx * 4];
      float ar[4] = {av.x, av.y, av.z, av.w};
      float br[4] = {bv.x, bv.y, bv.z, bv.w};
#pragma unroll
      for (int i = 0; i < 4; ++i)
#pragma unroll
        for (int j = 0; j < 4; ++j) acc[i][j] += ar[i] * br[j];
    }
  }
#pragma unroll
  for (int i = 0; i < 4; ++i) {
    float4 o;
    o.x = acc[i][0] + bias[bn + tx * 4 + 0];
    o.y = acc[i][1] + bias[bn + tx * 4 + 1];
    o.z = acc[i][2] + bias[bn + tx * 4 + 2];
    o.w = acc[i][3] + bias[bn + tx * 4 + 3];
    if (RELU) {
      o.x = fmaxf(o.x, 0.f); o.y = fmaxf(o.y, 0.f);
      o.z = fmaxf(o.z, 0.f); o.w = fmaxf(o.w, 0.f);
    }
    *(float4*)(C + (size_t)(bm + ty * 4 + i) * N + bn + tx * 4) = o;
  }
}

// ---------------- fused attention v2 ----------------
// 128 threads, 32 q-rows/block, grid (64, 8) -> 2 blocks/CU.
// Transposed staging Qt[d][q], Kt[d][k]: QK^T inner loop = 2 broadcast
// ds_read_b128 per d-step, conflict-free. Row max/sum via 16-lane shfl_xor
// butterfly (bitwise-identical across lanes). P through LDS transposed.
__global__ __launch_bounds__(128) void k_attn(const float* __restrict__ qkv,
                                              float* __restrict__ ob) {
  __shared__ float Qt[64][36];  // Qt[d][q]
  __shared__ float Kt[64][68];  // Kt[d][k]
  __shared__ float Vs[64][68];  // Vs[k][d]
  __shared__ float Pt[64][36];  // Pt[k][q]
  const int tid = threadIdx.x;
  const int bq = blockIdx.x * 32;
  const int h = blockIdx.y;
  // stage Q transposed, pre-scaled by 1/8
  {
    const int r = tid >> 2, ds0 = (tid & 3) * 16;
    const float* src = qkv + (size_t)(bq + r) * 1536 + h * DH + ds0;
#pragma unroll
    for (int i = 0; i < 4; ++i) {
      float4 v = *(const float4*)(src + i * 4);
      Qt[ds0 + i * 4 + 0][r] = v.x * 0.125f;
      Qt[ds0 + i * 4 + 1][r] = v.y * 0.125f;
      Qt[ds0 + i * 4 + 2][r] = v.z * 0.125f;
      Qt[ds0 + i * 4 + 3][r] = v.w * 0.125f;
    }
  }
  const int tx = tid & 15, ty = tid >> 4;  // tx: k/d group, ty: q group (0..7)
  float m[4], l[4], acc[4][4] = {};
#pragma unroll
  for (int i = 0; i < 4; ++i) { m[i] = -1e30f; l[i] = 0.f; }
  for (int kt = 0; kt < 32; ++kt) {
    __syncthreads();  // A: prev PV done reading Vs/Pt
    {
      const int r = tid >> 1, half = tid & 1;
      const float* ksrc = qkv + (size_t)(kt * 64 + r) * 1536 + 512 + h * DH + half * 32;
      const float* vsrc = ksrc + 512;
#pragma unroll
      for (int i = 0; i < 8; ++i) {
        float4 kv = *(const float4*)(ksrc + i * 4);
        int dd = half * 32 + i * 4;
        Kt[dd + 0][r] = kv.x; Kt[dd + 1][r] = kv.y;
        Kt[dd + 2][r] = kv.z; Kt[dd + 3][r] = kv.w;
      }
#pragma unroll
      for (int i = 0; i < 8; ++i)
        *(float4*)&Vs[r][half * 32 + i * 4] = *(const float4*)(vsrc + i * 4);
    }
    __syncthreads();  // B: staging done
    float s[4][4] = {};
#pragma unroll 8
    for (int d = 0; d < 64; ++d) {
      float4 qv = *(const float4*)&Qt[d][ty * 4];
      float4 kv = *(const float4*)&Kt[d][tx * 4];
      float qa[4] = {qv.x, qv.y, qv.z, qv.w};
      float ka[4] = {kv.x, kv.y, kv.z, kv.w};
#pragma unroll
      for (int i = 0; i < 4; ++i)
#pragma unroll
        for (int j = 0; j < 4; ++j) s[i][j] += qa[i] * ka[j];
    }
#pragma unroll
    for (int i = 0; i < 4; ++i) {
      // row max across j and across the 16 lanes of this q-row group
      float v = fmaxf(fmaxf(s[i][0], s[i][1]), fmaxf(s[i][2], s[i][3]));
#pragma unroll
      for (int off = 1; off < 16; off <<= 1) v = fmaxf(v, __shfl_xor(v, off, 64));
      float mn = fmaxf(m[i], v);
      float f = __expf(m[i] - mn);
      m[i] = mn;
      float p0 = __expf(s[i][0] - mn), p1 = __expf(s[i][1] - mn);
      float p2 = __expf(s[i][2] - mn), p3 = __expf(s[i][3] - mn);
      float rs = (p0 + p1) + (p2 + p3);
#pragma unroll
      for (int off = 1; off < 16; off <<= 1) rs += __shfl_xor(rs, off, 64);
      l[i] = l[i] * f + rs;
      acc[i][0] *= f; acc[i][1] *= f; acc[i][2] *= f; acc[i][3] *= f;
      const int q = ty * 4 + i;
      Pt[tx * 4 + 0][q] = p0; Pt[tx * 4 + 1][q] = p1;
      Pt[tx * 4 + 2][q] = p2; Pt[tx * 4 + 3][q] = p3;
    }
    __syncthreads();  // C: Pt ready
#pragma unroll 8
    for (int k = 0; k < 64; ++k) {
      float4 pv = *(const float4*)&Pt[k][ty * 4];
      float4 vv = *(const float4*)&Vs[k][tx * 4];
      float pa[4] = {pv.x, pv.y, pv.z, pv.w};
      float va[4] = {vv.x, vv.y, vv.z, vv.w};
#pragma unroll
      for (int i = 0; i < 4; ++i)
#pragma unroll
        for (int j = 0; j < 4; ++j) acc[i][j] += pa[i] * va[j];
    }
  }
#pragma unroll
  for (int i = 0; i < 4; ++i) {
    float inv = 1.f / l[i];
    float4 o;
    o.x = acc[i][0] * inv; o.y = acc[i][1] * inv;
    o.z = acc[i][2] * inv; o.w = acc[i][3] * inv;
    *(float4*)(ob + (size_t)(bq + ty * 4 + i) * D_MODEL + h * DH + tx * 4) = o;
  }
}

// ---------------- residual + layernorm ----------------
__global__ __launch_bounds__(128) void k_ln(const float* __restrict__ a,
                                            const float* __restrict__ r,
                                            const float* __restrict__ g,
                                            const float* __restrict__ b,
                                            float* __restrict__ out) {
  __shared__ float red[2];
  const int row = blockIdx.x, tid = threadIdx.x;
  const size_t off = (size_t)row * D_MODEL + tid * 4;
  float4 av = *(const float4*)(a + off);
  float4 rv = *(const float4*)(r + off);
  float v0 = av.x + rv.x, v1 = av.y + rv.y, v2 = av.z + rv.z, v3 = av.w + rv.w;
  float s = v0 + v1 + v2 + v3;
#pragma unroll
  for (int d = 1; d < 64; d <<= 1) s += __shfl_xor(s, d, 64);
  if ((tid & 63) == 0) red[tid >> 6] = s;
  __syncthreads();
  float mean = (red[0] + red[1]) * (1.f / 512.f);
  __syncthreads();
  float d0 = v0 - mean, d1 = v1 - mean, d2 = v2 - mean, d3 = v3 - mean;
  float sq = d0 * d0 + d1 * d1 + d2 * d2 + d3 * d3;
#pragma unroll
  for (int d = 1; d < 64; d <<= 1) sq += __shfl_xor(sq, d, 64);
  if ((tid & 63) == 0) red[tid >> 6] = sq;
  __syncthreads();
  float inv = rsqrtf((red[0] + red[1]) * (1.f / 512.f) + 1e-5f);
  float4 gv = *(const float4*)(g + tid * 4);
  float4 bv = *(const float4*)(b + tid * 4);
  float4 o;
  o.x = d0 * inv * gv.x + bv.x;
  o.y = d1 * inv * gv.y + bv.y;
  o.z = d2 * inv * gv.z + bv.z;
  o.w = d3 * inv * gv.w + bv.w;
  *(float4*)(out + off) = o;
}

// ---------------- emission scores feats = x2 * Wt^T + bt  [2048][32] ----------------
__global__ __launch_bounds__(256) void k_feats(const float* __restrict__ x2,
                                               const float* __restrict__ Wt,
                                               const float* __restrict__ bt,
                                               float* __restrict__ feats) {
  const int tid = threadIdx.x;
  const int s = blockIdx.x * 8 + (tid >> 5);
  const int l = tid & 31;
  const float* xr = x2 + (size_t)s * D_MODEL;
  const float* wr = Wt + (size_t)l * D_MODEL;
  float acc = 0.f;
#pragma unroll 8
  for (int k = 0; k < D_MODEL; k += 4) {
    float4 xv = *(const float4*)(xr + k);
    float4 wv = *(const float4*)(wr + k);
    acc += xv.x * wv.x + xv.y * wv.y + xv.z * wv.z + xv.w * wv.w;
  }
  feats[s * L_TAGS + l] = acc + bt[l];
}

// ---------------- Viterbi forward (serial, bitwise-exact f32), max only ----------------
__global__ __launch_bounds__(64) void k_vit_serial(const float* __restrict__ feats,
                                                   const float* __restrict__ T,
                                                   float* __restrict__ alphas,
                                                   float* __restrict__ out,
                                                   int* __restrict__ bestp) {
  const int l = threadIdx.x;
  const int n = l & 31, half = l >> 5;
  float Tr[16];
#pragma unroll
  for (int j = 0; j < 16; ++j) Tr[j] = T[n * 32 + half * 16 + j];
  int adr[16];
#pragma unroll
  for (int j = 0; j < 16; ++j) adr[j] = (half * 16 + j) * 4;
  float a = (n == START_TAG) ? 0.f : NEGV;
  alphas[n] = a;
  float e0 = feats[n], e1 = feats[32 + n], e2 = feats[64 + n], e3 = feats[96 + n];
  const float* fp = feats + 128 + n;
  float* ap = alphas + 32 + n;
  for (int t = 0; t < S_LEN; t += 2) {
    float eA = fp[0], eB = fp[32];
    fp += 64;
#pragma unroll
    for (int u = 0; u < 2; ++u) {
      float g[16];
#pragma unroll
      for (int j = 0; j < 16; ++j)
        g[j] = __int_as_float(__builtin_amdgcn_ds_bpermute(adr[j], __float_as_int(a))) + Tr[j];
      // depth-3 max tree via v_max3_f32
      float t0 = max3f(g[0], g[1], g[2]);
      float t1 = max3f(g[3], g[4], g[5]);
      float t2 = max3f(g[6], g[7], g[8]);
      float t3 = max3f(g[9], g[10], g[11]);
      float t4 = max3f(g[12], g[13], g[14]);
      float mx = fmaxf(max3f(t0, t1, t2), max3f(t3, t4, g[15]));
      uint2v r = __builtin_amdgcn_permlane32_swap(__float_as_uint(mx),
                                                  __float_as_uint(mx),
                                                  false, false);
      a = fmaxf(__uint_as_float(r[0]), __uint_as_float(r[1])) + (u == 0 ? e0 : e1);
      ap[u * 32] = a;
    }
    ap += 64;
    e0 = e2; e1 = e3; e2 = eA; e3 = eB;
  }
  float term = a + T[STOP_TAG * 32 + n];
  float bv = term;
  int bi = n;
#pragma unroll
  for (int d = 1; d < 32; d <<= 1) {
    float ov = __shfl_xor(bv, d, 64);
    int oi = __shfl_xor(bi, d, 64);
    if (ov > bv || (ov == bv && oi < bi)) { bv = ov; bi = oi; }
  }
  if (l == 0) { out[0] = bv; *bestp = bi; }
}

// ---------------- backpointers (parallel, exact) ----------------
__global__ __launch_bounds__(256) void k_vit_bp(const float* __restrict__ alphas,
                                                const float* __restrict__ T,
                                                unsigned char* __restrict__ bp) {
  __shared__ float Ts[32][33];
  __shared__ float Al[8][32];
  const int tid = threadIdx.x;
  for (int i = tid; i < 1024; i += 256) Ts[i >> 5][i & 31] = T[i];
  const int t0 = blockIdx.x * 8;
  Al[tid >> 5][tid & 31] = alphas[t0 * 32 + tid];
  __syncthreads();
  const int tl = tid >> 5, n = tid & 31;
  float best = -3e38f;
  int bi = 0;
#pragma unroll
  for (int p = 0; p < 32; ++p) {
    float v = Al[tl][p] + Ts[n][p];
    if (v > best) { best = v; bi = p; }
  }
  bp[(size_t)(t0 + tl) * 32 + n] = (unsigned char)bi;
}

// ---------------- traceback ----------------
__global__ __launch_bounds__(256) void k_vit_trace(const unsigned char* __restrict__ bp,
                                                   const int* __restrict__ bestp,
                                                   unsigned char* __restrict__ cand,
                                                   float* __restrict__ outp) {
  __shared__ unsigned char Amap[64][32];
  const int tid = threadIdx.x;
  int tg[8];
#pragma unroll
  for (int i = 0; i < 8; ++i) {
    int id = tid + 256 * i;
    tg[i] = id & 31;
    cand[(size_t)id * 32 + 31] = (unsigned char)tg[i];
  }
  for (int j = 31; j >= 1; --j) {
#pragma unroll
    for (int i = 0; i < 8; ++i) {
      int id = tid + 256 * i;
      tg[i] = bp[(size_t)((id >> 5) * 32 + j) * 32 + tg[i]];
      cand[(size_t)id * 32 + (j - 1)] = (unsigned char)tg[i];
    }
  }
#pragma unroll
  for (int i = 0; i < 8; ++i) {
    int id = tid + 256 * i;
    Amap[id >> 5][id & 31] = bp[(size_t)((id >> 5) * 32) * 32 + tg[i]];
  }
  __syncthreads();
  for (int d = 1; d < 64; d <<= 1) {
    unsigned char tmpv[8];
#pragma unroll
    for (int i = 0; i < 8; ++i) {
      int id = tid + 256 * i;
      int c = id >> 5, e = id & 31;
      tmpv[i] = (c + d < 64) ? Amap[c][Amap[c + d][e]] : Amap[c][e];
    }
    __syncthreads();
#pragma unroll
    for (int i = 0; i < 8; ++i) {
      int id = tid + 256 * i;
      Amap[id >> 5][id & 31] = tmpv[i];
    }
    __syncthreads();
  }
  const int best = *bestp;
#pragma unroll
  for (int i = 0; i < 8; ++i) {
    int t = tid + 256 * i;
    int c = t >> 5, j = t & 31;
    int et = (c == 63) ? best : Amap[c + 1][best];
    outp[1 + t] = (float)cand[(size_t)(c * 32 + et) * 32 + j];
  }
}

extern "C" void kernel_launch(void* const* d_in, const int* in_sizes, int n_in,
                              void* d_out, int out_size, void* d_ws, size_t ws_size,
                              hipStream_t stream) {
  (void)in_sizes; (void)n_in; (void)out_size; (void)ws_size;
  const int* sent = (const int*)d_in[0];
  const float* embed = (const float*)d_in[1];
  const float* Wqkv = (const float*)d_in[2];
  const float* bqkv = (const float*)d_in[3];
  const float* Wo = (const float*)d_in[4];
  const float* bo = (const float*)d_in[5];
  const float* g1 = (const float*)d_in[6];
  const float* b1n = (const float*)d_in[7];
  const float* W1 = (const float*)d_in[8];
  const float* b1f = (const float*)d_in[9];
  const float* W2 = (const float*)d_in[10];
  const float* b2f = (const float*)d_in[11];
  const float* g2 = (const float*)d_in[12];
  const float* b2n = (const float*)d_in[13];
  const float* Wt = (const float*)d_in[14];
  const float* bt = (const float*)d_in[15];
  const float* T = (const float*)d_in[16];
  float* out = (float*)d_out;

  float* ws = (float*)d_ws;
  const size_t M1 = 1u << 20;  // 1M floats = 4MB
  float* x = ws;               // [2048][512]
  float* qkvb = ws + M1;       // [2048][1536]
  float* ob = ws + 4 * M1;     // [2048][512]
  float* yb = ws + 5 * M1;     // [2048][512]
  float* x1 = ws + 6 * M1;     // [2048][512]
  float* ffb = ws;             // [2048][2048]  (aliases x+qkvb, dead by then)
  float* zb = ws + 4 * M1;     // aliases ob
  float* x2 = ws + 5 * M1;     // aliases yb
  float* feats = ws + 7 * M1;  // [2048][32]
  float* alphas = feats + 2048 * 32;            // [2049][32]
  int* bestp = (int*)(alphas + 2049 * 32 + 32);
  unsigned char* bp = (unsigned char*)(bestp + 32);  // [2048][32] u8
  unsigned char* cand = bp + 2048 * 32;              // [2048][32] u8

  k_embed<<<dim3(2048), dim3(128), 0, stream>>>(sent, embed, x);
  k_gemm128<false><<<dim3(12, 16), dim3(256), 0, stream>>>(x, Wqkv, bqkv, qkvb, 2048, 1536, 512);
  k_attn<<<dim3(64, 8), dim3(128), 0, stream>>>(qkvb, ob);
  k_gemm64<false><<<dim3(8, 32), dim3(256), 0, stream>>>(ob, Wo, bo, yb, 2048, 512, 512);
  k_ln<<<dim3(2048), dim3(128), 0, stream>>>(x, yb, g1, b1n, x1);
  k_gemm128<true><<<dim3(16, 16), dim3(256), 0, stream>>>(x1, W1, b1f, ffb, 2048, 2048, 512);
  k_gemm64<false><<<dim3(8, 32), dim3(256), 0, stream>>>(ffb, W2, b2f, zb, 2048, 512, 2048);
  k_ln<<<dim3(2048), dim3(128), 0, stream>>>(x1, zb, g2, b2n, x2);
  k_feats<<<dim3(256), dim3(256), 0, stream>>>(x2, Wt, bt, feats);
  k_vit_serial<<<dim3(1), dim3(64), 0, stream>>>(feats, T, alphas, out, bestp);
  k_vit_bp<<<dim3(256), dim3(256), 0, stream>>>(alphas, T, bp);
  k_vit_trace<<<dim3(1), dim3(256), 0, stream>>>(bp, bestp, cand, out);
}